// Round 1
// baseline (10.117 us; speedup 1.0000x reference)
//
#include <hip/hip_runtime.h>
#include <hip/hip_bf16.h>

// PQC classifier: the circuit output is independent of the batch input x.
// Analytic reduction:
//   <Z0> = cos(theta_rx), <Z1> = cos(theta_ry), <Z2> = <Z3> = 1
//   logits = (cos tx + cos ty, 2); out = log_softmax(logits) broadcast to (bsz, 2).
// Kernel = compute 2 scalars per thread (uniform), store 8 MB of float4s.

__global__ void pqc_broadcast_kernel(const float* __restrict__ theta_rx,
                                     const float* __restrict__ theta_ry,
                                     float* __restrict__ out,
                                     int n4) {
    // Uniform scalar math (identical in every lane; L2-broadcast loads).
    float cx = cosf(theta_rx[0]);
    float cy = cosf(theta_ry[0]);
    float l0 = cx + cy;
    float l1 = 2.0f;
    float m  = fmaxf(l0, l1);
    float lse = m + logf(expf(l0 - m) + expf(l1 - m));
    float o0 = l0 - lse;
    float o1 = l1 - lse;

    float4 v = make_float4(o0, o1, o0, o1);
    int i = blockIdx.x * blockDim.x + threadIdx.x;
    if (i < n4) {
        reinterpret_cast<float4*>(out)[i] = v;
    }
}

extern "C" void kernel_launch(void* const* d_in, const int* in_sizes, int n_in,
                              void* d_out, int out_size, void* d_ws, size_t ws_size,
                              hipStream_t stream) {
    // Inputs (setup_inputs order): x (bsz*16 f32), theta_rx (1), theta_ry (1), theta_rz (1).
    const float* theta_rx = (const float*)d_in[1];
    const float* theta_ry = (const float*)d_in[2];
    float* out = (float*)d_out;

    // out_size = bsz * 2 floats; bsz = 2^20 so divisible by 4.
    int n4 = out_size / 4;  // float4 stores, each covering 2 output rows
    int block = 256;
    int grid = (n4 + block - 1) / block;
    pqc_broadcast_kernel<<<grid, block, 0, stream>>>(theta_rx, theta_ry, out, n4);
}